// Round 2
// baseline (332.599 us; speedup 1.0000x reference)
//
#include <hip/hip_runtime.h>

#define Bb 8
#define Cc 8
#define Ff 257
#define Tt 1500
#define P2 750            // Tt/2 (float2 elements)
#define BF (Bb*Ff)        // 2056

__device__ __forceinline__ constexpr int utIdx(int c, int d) { return c*(17-c)/2 + (d-c); }      // c<=d, 36 vals
__device__ __forceinline__ constexpr int odIdx(int c, int d) { return 7*c - c*(c-1)/2 + (d-c-1); } // c<d, 28 vals

constexpr float EPSv   = 1e-8f;
constexpr float PSDEPS = 1e-5f;
constexpr float IMADD  = 1e-5f + 1e-8f;   // +1j*PSD_EPS (inside _estimate_psd) +1j*eps (outside)

// ---------------- mask max, stage 1: partial max over F-chunks ----------------
__global__ void mask_pmax(const float* __restrict__ sm, const float* __restrict__ nm,
                          float* __restrict__ pmax_s, float* __restrict__ pmax_n) {
    int t  = blockIdx.x * 256 + threadIdx.x;
    int ch = blockIdx.y;
    int b  = blockIdx.z;
    if (t >= Tt) return;
    int f0 = ch * 33, f1 = min(Ff, f0 + 33);
    float ms = 0.f, mn = 0.f;
    for (int f = f0; f < f1; ++f) {
        ms = fmaxf(ms, fabsf(sm[(b*Ff + f)*Tt + t]));
        mn = fmaxf(mn, fabsf(nm[(b*Ff + f)*Tt + t]));
    }
    pmax_s[(b*8 + ch)*Tt + t] = ms;
    pmax_n[(b*8 + ch)*Tt + t] = mn;
}

// ---------------- mask max, stage 2: combine chunks -> 1/(max+eps) ----------------
__global__ void mask_inv(const float* __restrict__ pmax_s, const float* __restrict__ pmax_n,
                         float* __restrict__ inv_s, float* __restrict__ inv_n) {
    int t = blockIdx.x * 256 + threadIdx.x;
    int b = blockIdx.y;
    if (t >= Tt) return;
    float ms = 0.f, mn = 0.f;
    #pragma unroll
    for (int ch = 0; ch < 8; ++ch) {
        ms = fmaxf(ms, pmax_s[(b*8 + ch)*Tt + t]);
        mn = fmaxf(mn, pmax_n[(b*8 + ch)*Tt + t]);
    }
    inv_s[b*Tt + t] = 1.0f / (ms + EPSv);
    inv_n[b*Tt + t] = 1.0f / (mn + EPSv);
}

// ---------------- main fused kernel: one block (1 wave) per (b,f) ----------------
// __launch_bounds__(64,1): phase A holds ~190 live regs (128 accumulators + loads);
// min-waves=1 lets the allocator take them without AGPR/scratch spills (gfx950
// unified file, no spill through ~450 regs). Occupancy stays 2 waves/SIMD
// (LDS 19.4 KB -> 8 blocks/CU) as long as VGPR <= 256.
__global__ __launch_bounds__(64, 1) void mvdr_main(
    const float* __restrict__ smask, const float* __restrict__ nmask,
    const float* __restrict__ cmr,   const float* __restrict__ cmi,
    const float* __restrict__ inv_s, const float* __restrict__ inv_n,
    float* __restrict__ out)
{
    const int blk = blockIdx.x;
    const int b = blk / Ff, f = blk % Ff;
    const int tid = threadIdx.x;

    const float2* sm2 = (const float2*)smask + (b*Ff + f)*P2;
    const float2* nm2 = (const float2*)nmask + (b*Ff + f)*P2;
    const float2* is2 = (const float2*)inv_s + b*P2;
    const float2* in2 = (const float2*)inv_n + b*P2;
    const int cstride = Ff * P2;                       // float2 per (b,c) plane
    const float2* xr2 = (const float2*)cmr + (b*Cc)*cstride + f*P2;
    const float2* xi2 = (const float2*)cmi + (b*Cc)*cstride + f*P2;

    // ---- Phase A: weighted covariance accumulation (registers) ----
    float accS[64], accN[64];
    #pragma unroll
    for (int v = 0; v < 64; ++v) { accS[v] = 0.f; accN[v] = 0.f; }
    float sum_ms = 0.f, sum_mn = 0.f;

    for (int p = tid; p < P2; p += 64) {
        float2 s2  = sm2[p], n2v = nm2[p];
        float2 i2s = is2[p], i2n = in2[p];
        float2 xr[8], xi[8];
        #pragma unroll
        for (int c = 0; c < 8; ++c) { xr[c] = xr2[p + c*cstride]; xi[c] = xi2[p + c*cstride]; }
        float msx = s2.x * i2s.x, msy = s2.y * i2s.y;
        float mnx = n2v.x * i2n.x, mny = n2v.y * i2n.y;
        sum_ms += msx + msy; sum_mn += mnx + mny;
        // shared products: S and N reuse p1/p2/q1/q2
        #pragma unroll
        for (int c = 0; c < 8; ++c) {
            {
                float p1 = xr[c].x*xr[c].x + xi[c].x*xi[c].x;
                float p2 = xr[c].y*xr[c].y + xi[c].y*xi[c].y;
                const int k = utIdx(c, c);
                accS[k] += msx*p1 + msy*p2;
                accN[k] += mnx*p1 + mny*p2;
            }
            #pragma unroll
            for (int d = c + 1; d < 8; ++d) {
                float p1 = xr[c].x*xr[d].x + xi[c].x*xi[d].x;
                float p2 = xr[c].y*xr[d].y + xi[c].y*xi[d].y;
                float q1 = xi[c].x*xr[d].x - xr[c].x*xi[d].x;
                float q2 = xi[c].y*xr[d].y - xr[c].y*xi[d].y;
                const int k = utIdx(c, d);
                const int j = 36 + odIdx(c, d);
                accS[k] += msx*p1 + msy*p2;
                accN[k] += mnx*p1 + mny*p2;
                accS[j] += msx*q1 + msy*q2;
                accN[j] += mnx*q1 + mny*q2;
            }
        }
    }

    // mask sums: wave butterfly (only 2 values)
    #pragma unroll
    for (int o = 32; o; o >>= 1) {
        sum_ms += __shfl_xor(sum_ms, o, 64);
        sum_mn += __shfl_xor(sum_mn, o, 64);
    }
    const float den_s = fmaxf(sum_ms, PSDEPS);
    const float den_n = fmaxf(sum_mn, PSDEPS);

    // ---- cross-lane reduction: LDS transpose, 2 rounds of 64 values ----
    __shared__ float red[64*68];
    #pragma unroll
    for (int v = 0; v < 64; ++v) red[v*68 + tid] = accS[v];
    __syncthreads();
    float Sval = 0.f;
    {
        const float4* row = (const float4*)(red + tid*68);
        #pragma unroll
        for (int q = 0; q < 16; ++q) { float4 r4 = row[q]; Sval += r4.x + r4.y + r4.z + r4.w; }
    }
    __syncthreads();
    #pragma unroll
    for (int v = 0; v < 64; ++v) red[v*68 + tid] = accN[v];
    __syncthreads();
    float Nval = 0.f;
    {
        const float4* row = (const float4*)(red + tid*68);
        #pragma unroll
        for (int q = 0; q < 16; ++q) { float4 r4 = row[q]; Nval += r4.x + r4.y + r4.z + r4.w; }
    }

    // ---- build S matrix and augmented [N | I] in LDS ----
    __shared__ float SreM[64], SimM[64];
    __shared__ float Are[128], Aim[128];
    __shared__ float dre[8], dim_[8], wre[8], wim[8];

    {
        int cc_, dd_;
        if (tid < 36) { int k = tid, c = 0; while (k >= 8 - c) { k -= 8 - c; ++c; } cc_ = c; dd_ = c + k; }
        else          { int k = tid - 36, c = 0; while (k >= 7 - c) { k -= 7 - c; ++c; } cc_ = c; dd_ = c + k + 1; }
        float sv = Sval / den_s, nv = Nval / den_n;
        if (tid < 36) {
            SreM[cc_*8 + dd_] = sv; SreM[dd_*8 + cc_] = sv;
            float nvd = nv + (cc_ == dd_ ? EPSv : 0.f);   // + eye*eps on noise diag
            Are[cc_*16 + dd_] = nvd; Are[dd_*16 + cc_] = nvd;
            if (cc_ == dd_) { SimM[cc_*8 + cc_] = IMADD; Aim[cc_*16 + cc_] = IMADD; }
        } else {
            SimM[cc_*8 + dd_] = IMADD + sv; SimM[dd_*8 + cc_] = IMADD - sv;
            Aim[cc_*16 + dd_] = IMADD + nv; Aim[dd_*16 + cc_] = IMADD - nv;
        }
        int r = tid >> 3, j = tid & 7;                    // identity right half
        Are[r*16 + 8 + j] = (r == j) ? 1.f : 0.f;
        Aim[r*16 + 8 + j] = 0.f;
    }
    __syncthreads();

    // ---- Gauss-Jordan inverse of N (unpivoted; N ~ HPD + tiny perturbation) ----
    // lane owns cells (r, cA) and (r, cA+8) of the 8x16 augmented matrix
    {
        const int r = tid >> 3, cA = tid & 7;
        for (int k = 0; k < 8; ++k) {
            float pr = Are[k*16 + k], pi = Aim[k*16 + k];
            float idn = 1.0f / (pr*pr + pi*pi);
            float ipr = pr*idn, ipi = -pi*idn;
            if (r == k) {
                float ar0 = Are[k*16 + cA],     ai0 = Aim[k*16 + cA];
                Are[k*16 + cA]     = ar0*ipr - ai0*ipi; Aim[k*16 + cA]     = ar0*ipi + ai0*ipr;
                float ar1 = Are[k*16 + cA + 8], ai1 = Aim[k*16 + cA + 8];
                Are[k*16 + cA + 8] = ar1*ipr - ai1*ipi; Aim[k*16 + cA + 8] = ar1*ipi + ai1*ipr;
            }
            __syncthreads();
            float fr = Are[r*16 + k], fi = Aim[r*16 + k];
            float p0r = Are[k*16 + cA],     p0i = Aim[k*16 + cA];
            float p1r = Are[k*16 + cA + 8], p1i = Aim[k*16 + cA + 8];
            float o0r = 0.f, o0i = 0.f, o1r = 0.f, o1i = 0.f;
            if (r != k) {
                o0r = Are[r*16 + cA]     - (fr*p0r - fi*p0i);
                o0i = Aim[r*16 + cA]     - (fr*p0i + fi*p0r);
                o1r = Are[r*16 + cA + 8] - (fr*p1r - fi*p1i);
                o1i = Aim[r*16 + cA + 8] - (fr*p1i + fi*p1r);
            }
            __syncthreads();
            if (r != k) {
                Are[r*16 + cA]     = o0r; Aim[r*16 + cA]     = o0i;
                Are[r*16 + cA + 8] = o1r; Aim[r*16 + cA + 8] = o1i;
            }
            __syncthreads();
        }
    }

    // ---- u = inv@S e0, partial traces ----
    if (tid < 8) {
        int c = tid;
        float ur = 0.f, ui = 0.f, tr_r = 0.f, tr_i = 0.f;
        #pragma unroll
        for (int j = 0; j < 8; ++j) {
            float vr = Are[c*16 + 8 + j], vi = Aim[c*16 + 8 + j] + EPSv;  // inv + 1j*eps
            float s0r = SreM[j*8 + 0], s0i = SimM[j*8 + 0];
            ur += vr*s0r - vi*s0i; ui += vr*s0i + vi*s0r;
            float scr = SreM[j*8 + c], sci = SimM[j*8 + c];
            tr_r += vr*scr - vi*sci; tr_i += vr*sci + vi*scr;
        }
        dre[c] = tr_r; dim_[c] = tr_i;
        wre[c] = ur;   wim[c]  = ui;
    }
    __syncthreads();
    if (tid < 8) {
        float tr_r = EPSv, tr_i = 0.f;
        #pragma unroll
        for (int j = 0; j < 8; ++j) { tr_r += dre[j]; tr_i += dim_[j]; }
        float idn = 1.0f / (tr_r*tr_r + tr_i*tr_i);
        float ur = wre[tid], ui = wim[tid];
        wre[tid] = (ur*tr_r + ui*tr_i) * idn;     // w = u * conj(tr) / |tr|^2
        wim[tid] = (ui*tr_r - ur*tr_i) * idn;
    }
    __syncthreads();

    // ---- Phase B: out[b,f,t] = sum_c conj(w_c) * x_c(t) ----
    float wr[8], wi[8];
    #pragma unroll
    for (int c = 0; c < 8; ++c) { wr[c] = wre[c]; wi[c] = wim[c]; }

    float2* outr = (float2*)out + (b*Ff + f)*P2;
    float2* outi = (float2*)out + (Bb*Ff)*P2 + (b*Ff + f)*P2;
    for (int p = tid; p < P2; p += 64) {
        float rx = 0.f, ry = 0.f, ix = 0.f, iy = 0.f;
        #pragma unroll
        for (int c = 0; c < 8; ++c) {
            float2 a  = xr2[p + c*cstride];
            float2 bb = xi2[p + c*cstride];
            rx += wr[c]*a.x + wi[c]*bb.x;
            ry += wr[c]*a.y + wi[c]*bb.y;
            ix += wr[c]*bb.x - wi[c]*a.x;
            iy += wr[c]*bb.y - wi[c]*a.y;
        }
        outr[p] = make_float2(rx, ry);
        outi[p] = make_float2(ix, iy);
    }
}

extern "C" void kernel_launch(void* const* d_in, const int* in_sizes, int n_in,
                              void* d_out, int out_size, void* d_ws, size_t ws_size,
                              hipStream_t stream) {
    const float* smask = (const float*)d_in[0];
    const float* nmask = (const float*)d_in[1];
    const float* cmr   = (const float*)d_in[2];
    const float* cmi   = (const float*)d_in[3];
    float* ws = (float*)d_ws;
    float* pmax_s = ws;                 // 8*8*1500 = 96000 floats
    float* pmax_n = ws + 96000;         // 96000
    float* inv_s  = ws + 192000;        // 12000
    float* inv_n  = ws + 204000;        // 12000  (total 864 KB)

    mask_pmax<<<dim3(6, 8, 8), 256, 0, stream>>>(smask, nmask, pmax_s, pmax_n);
    mask_inv <<<dim3(6, 8),    256, 0, stream>>>(pmax_s, pmax_n, inv_s, inv_n);
    mvdr_main<<<BF, 64, 0, stream>>>(smask, nmask, cmr, cmi, inv_s, inv_n, (float*)d_out);
}

// Round 3
// 301.353 us; speedup vs baseline: 1.1037x; 1.1037x over previous
//
#include <hip/hip_runtime.h>

#define Bb 8
#define Cc 8
#define Ff 257
#define Tt 1500
#define P2 750            // Tt/2 (float2 elements)
#define BF (Bb*Ff)        // 2056

__device__ __forceinline__ constexpr int utIdx(int c, int d) { return c*(17-c)/2 + (d-c); }      // c<=d, 36 vals
__device__ __forceinline__ constexpr int odIdx(int c, int d) { return 7*c - c*(c-1)/2 + (d-c-1); } // c<d, 28 vals

constexpr float EPSv   = 1e-8f;
constexpr float PSDEPS = 1e-5f;
constexpr float IMADD  = 1e-5f + 1e-8f;   // +1j*PSD_EPS (inside _estimate_psd) +1j*eps (outside)

// ---------------- mask max, stage 1: partial max over F-chunks ----------------
__global__ void mask_pmax(const float* __restrict__ sm, const float* __restrict__ nm,
                          float* __restrict__ pmax_s, float* __restrict__ pmax_n) {
    int t  = blockIdx.x * 256 + threadIdx.x;
    int ch = blockIdx.y;
    int b  = blockIdx.z;
    if (t >= Tt) return;
    int f0 = ch * 33, f1 = min(Ff, f0 + 33);
    float ms = 0.f, mn = 0.f;
    for (int f = f0; f < f1; ++f) {
        ms = fmaxf(ms, fabsf(sm[(b*Ff + f)*Tt + t]));
        mn = fmaxf(mn, fabsf(nm[(b*Ff + f)*Tt + t]));
    }
    pmax_s[(b*8 + ch)*Tt + t] = ms;
    pmax_n[(b*8 + ch)*Tt + t] = mn;
}

// ---------------- mask max, stage 2: combine chunks -> 1/(max+eps) ----------------
__global__ void mask_inv(const float* __restrict__ pmax_s, const float* __restrict__ pmax_n,
                         float* __restrict__ inv_s, float* __restrict__ inv_n) {
    int t = blockIdx.x * 256 + threadIdx.x;
    int b = blockIdx.y;
    if (t >= Tt) return;
    float ms = 0.f, mn = 0.f;
    #pragma unroll
    for (int ch = 0; ch < 8; ++ch) {
        ms = fmaxf(ms, pmax_s[(b*8 + ch)*Tt + t]);
        mn = fmaxf(mn, pmax_n[(b*8 + ch)*Tt + t]);
    }
    inv_s[b*Tt + t] = 1.0f / (ms + EPSv);
    inv_n[b*Tt + t] = 1.0f / (mn + EPSv);
}

// ---------------- main fused kernel: one block (4 waves) per (b,f) ----------------
// 256 threads: lane-parity mask split (even lanes: speech, odd: noise), pairs of
// lanes share one time sample. 64 accumulators/lane keeps VGPR ~<=160 so
// __launch_bounds__(256,3) holds >=3 waves/SIMD; 2056 blocks x 4 waves = 8224
// waves gives ~12+ resident waves/CU (vs 3 before) for latency hiding.
__global__ __launch_bounds__(256, 3) void mvdr_main(
    const float* __restrict__ smask, const float* __restrict__ nmask,
    const float* __restrict__ cmr,   const float* __restrict__ cmi,
    const float* __restrict__ inv_s, const float* __restrict__ inv_n,
    float* __restrict__ out)
{
    const int blk = blockIdx.x;
    const int b = blk / Ff, f = blk % Ff;
    const int tid  = threadIdx.x;
    const int par  = tid & 1;          // 0: speech, 1: noise
    const int pair = tid >> 1;         // [0,128): time-sample pair index
    const int wid  = tid >> 6;         // wave id [0,4)
    const int lane = tid & 63;

    const float2* sm2 = (const float2*)smask + (b*Ff + f)*P2;
    const float2* nm2 = (const float2*)nmask + (b*Ff + f)*P2;
    const float2* is2 = (const float2*)inv_s + b*P2;
    const float2* in2 = (const float2*)inv_n + b*P2;
    const float2* m2  = par ? nm2 : sm2;
    const float2* iv2 = par ? in2 : is2;
    const int cstride = Ff * P2;                       // float2 per (b,c) plane
    const float2* xr2 = (const float2*)cmr + (b*Cc)*cstride + f*P2;
    const float2* xi2 = (const float2*)cmi + (b*Cc)*cstride + f*P2;

    // ---- Phase A: weighted covariance accumulation (one mask per lane) ----
    float acc[64];
    #pragma unroll
    for (int v = 0; v < 64; ++v) acc[v] = 0.f;
    float summ = 0.f;

    int p = pair;
    #pragma unroll 1
    for (int it = 0; it < 6; ++it, p += 128) {
        if (p < P2) {
            float2 mk = m2[p], iv = iv2[p];
            float2 xr[8], xi[8];
            #pragma unroll
            for (int c = 0; c < 8; ++c) { xr[c] = xr2[p + c*cstride]; xi[c] = xi2[p + c*cstride]; }
            float mx = mk.x * iv.x, my = mk.y * iv.y;
            summ += mx + my;
            #pragma unroll
            for (int c = 0; c < 8; ++c) {
                float ax = mx*xr[c].x, ay = my*xr[c].y, bx = mx*xi[c].x, by = my*xi[c].y;
                {   // diagonal
                    const int k = utIdx(c, c);
                    float t0 = acc[k];
                    t0 = fmaf(ax, xr[c].x, t0); t0 = fmaf(bx, xi[c].x, t0);
                    t0 = fmaf(ay, xr[c].y, t0); t0 = fmaf(by, xi[c].y, t0);
                    acc[k] = t0;
                }
                #pragma unroll
                for (int d = c + 1; d < 8; ++d) {
                    const int k = utIdx(c, d);
                    const int j = 36 + odIdx(c, d);
                    float t0 = acc[k], t1 = acc[j];
                    t0 = fmaf(ax, xr[d].x, t0); t0 = fmaf(bx, xi[d].x, t0);
                    t0 = fmaf(ay, xr[d].y, t0); t0 = fmaf(by, xi[d].y, t0);
                    t1 = fmaf(bx, xr[d].x, t1); t1 = fmaf(-ax, xi[d].x, t1);
                    t1 = fmaf(by, xr[d].y, t1); t1 = fmaf(-ay, xi[d].y, t1);
                    acc[k] = t0; acc[j] = t1;
                }
            }
        }
    }

    // ---- mask-sum reduction: parity-preserving butterfly within each wave ----
    #pragma unroll
    for (int o = 2; o <= 32; o <<= 1) summ += __shfl_xor(summ, o, 64);
    __shared__ float msum[4], nsum[4];
    if (lane == 0) msum[wid] = summ;          // even-lane total = speech
    if (lane == 1) nsum[wid] = summ;          // odd-lane total  = noise

    // ---- value reduction: DPP butterfly (strides 2,4) -> 32 cols -> LDS transpose ----
    #pragma unroll
    for (int v = 0; v < 64; ++v) {
        acc[v] += __shfl_xor(acc[v], 2, 64);
        acc[v] += __shfl_xor(acc[v], 4, 64);
    }
    __shared__ float red[64*36];              // 9216 B; rows 16B-aligned
    const int col = wid*8 + (lane >> 3);      // [0,32) per parity round
    if (par == 0 && (lane & 7) == 0) {
        #pragma unroll
        for (int v = 0; v < 64; ++v) red[v*36 + col] = acc[v];
    }
    __syncthreads();
    float Sval = 0.f;
    if (tid < 64) {
        const float4* row = (const float4*)(red + tid*36);
        #pragma unroll
        for (int k = 0; k < 8; ++k) { float4 r4 = row[k]; Sval += r4.x + r4.y + r4.z + r4.w; }
    }
    __syncthreads();
    if (par == 1 && (lane & 7) == 1) {
        #pragma unroll
        for (int v = 0; v < 64; ++v) red[v*36 + col] = acc[v];
    }
    __syncthreads();
    float Nval = 0.f;
    if (tid < 64) {
        const float4* row = (const float4*)(red + tid*36);
        #pragma unroll
        for (int k = 0; k < 8; ++k) { float4 r4 = row[k]; Nval += r4.x + r4.y + r4.z + r4.w; }
    }

    // ---- build S matrix and augmented [N | I] in LDS (threads 0..63) ----
    __shared__ float SreM[64], SimM[64];
    __shared__ float Are[128], Aim[128];
    __shared__ float dre[8], dim_[8], wre[8], wim[8];

    if (tid < 64) {
        const float den_s = fmaxf(msum[0]+msum[1]+msum[2]+msum[3], PSDEPS);
        const float den_n = fmaxf(nsum[0]+nsum[1]+nsum[2]+nsum[3], PSDEPS);
        int cc_, dd_;
        if (tid < 36) { int k = tid, c = 0; while (k >= 8 - c) { k -= 8 - c; ++c; } cc_ = c; dd_ = c + k; }
        else          { int k = tid - 36, c = 0; while (k >= 7 - c) { k -= 7 - c; ++c; } cc_ = c; dd_ = c + k + 1; }
        float sv = Sval / den_s, nv = Nval / den_n;
        if (tid < 36) {
            SreM[cc_*8 + dd_] = sv; SreM[dd_*8 + cc_] = sv;
            float nvd = nv + (cc_ == dd_ ? EPSv : 0.f);   // + eye*eps on noise diag
            Are[cc_*16 + dd_] = nvd; Are[dd_*16 + cc_] = nvd;
            if (cc_ == dd_) { SimM[cc_*8 + cc_] = IMADD; Aim[cc_*16 + cc_] = IMADD; }
        } else {
            SimM[cc_*8 + dd_] = IMADD + sv; SimM[dd_*8 + cc_] = IMADD - sv;
            Aim[cc_*16 + dd_] = IMADD + nv; Aim[dd_*16 + cc_] = IMADD - nv;
        }
        int r = tid >> 3, j = tid & 7;                    // identity right half
        Are[r*16 + 8 + j] = (r == j) ? 1.f : 0.f;
        Aim[r*16 + 8 + j] = 0.f;
    }
    __syncthreads();

    // ---- Gauss-Jordan inverse of N (unpivoted; N ~ HPD + tiny perturbation) ----
    // active threads tid<64: lane owns cells (r, cA) and (r, cA+8); all 256
    // threads hit the top-level __syncthreads.
    {
        const bool act = tid < 64;
        const int r = (tid >> 3) & 7, cA = tid & 7;
        for (int k = 0; k < 8; ++k) {
            float pr = Are[k*16 + k], pi = Aim[k*16 + k];
            float idn = 1.0f / (pr*pr + pi*pi);
            float ipr = pr*idn, ipi = -pi*idn;
            if (act && r == k) {
                float ar0 = Are[k*16 + cA],     ai0 = Aim[k*16 + cA];
                Are[k*16 + cA]     = ar0*ipr - ai0*ipi; Aim[k*16 + cA]     = ar0*ipi + ai0*ipr;
                float ar1 = Are[k*16 + cA + 8], ai1 = Aim[k*16 + cA + 8];
                Are[k*16 + cA + 8] = ar1*ipr - ai1*ipi; Aim[k*16 + cA + 8] = ar1*ipi + ai1*ipr;
            }
            __syncthreads();
            float fr = Are[r*16 + k], fi = Aim[r*16 + k];
            float p0r = Are[k*16 + cA],     p0i = Aim[k*16 + cA];
            float p1r = Are[k*16 + cA + 8], p1i = Aim[k*16 + cA + 8];
            float o0r = 0.f, o0i = 0.f, o1r = 0.f, o1i = 0.f;
            if (r != k) {
                o0r = Are[r*16 + cA]     - (fr*p0r - fi*p0i);
                o0i = Aim[r*16 + cA]     - (fr*p0i + fi*p0r);
                o1r = Are[r*16 + cA + 8] - (fr*p1r - fi*p1i);
                o1i = Aim[r*16 + cA + 8] - (fr*p1i + fi*p1r);
            }
            __syncthreads();
            if (act && r != k) {
                Are[r*16 + cA]     = o0r; Aim[r*16 + cA]     = o0i;
                Are[r*16 + cA + 8] = o1r; Aim[r*16 + cA + 8] = o1i;
            }
            __syncthreads();
        }
    }

    // ---- u = inv@S e0, partial traces ----
    if (tid < 8) {
        int c = tid;
        float ur = 0.f, ui = 0.f, tr_r = 0.f, tr_i = 0.f;
        #pragma unroll
        for (int j = 0; j < 8; ++j) {
            float vr = Are[c*16 + 8 + j], vi = Aim[c*16 + 8 + j] + EPSv;  // inv + 1j*eps
            float s0r = SreM[j*8 + 0], s0i = SimM[j*8 + 0];
            ur += vr*s0r - vi*s0i; ui += vr*s0i + vi*s0r;
            float scr = SreM[j*8 + c], sci = SimM[j*8 + c];
            tr_r += vr*scr - vi*sci; tr_i += vr*sci + vi*scr;
        }
        dre[c] = tr_r; dim_[c] = tr_i;
        wre[c] = ur;   wim[c]  = ui;
    }
    __syncthreads();
    if (tid < 8) {
        float tr_r = EPSv, tr_i = 0.f;
        #pragma unroll
        for (int j = 0; j < 8; ++j) { tr_r += dre[j]; tr_i += dim_[j]; }
        float idn = 1.0f / (tr_r*tr_r + tr_i*tr_i);
        float ur = wre[tid], ui = wim[tid];
        wre[tid] = (ur*tr_r + ui*tr_i) * idn;     // w = u * conj(tr) / |tr|^2
        wim[tid] = (ui*tr_r - ur*tr_i) * idn;
    }
    __syncthreads();

    // ---- Phase B: out[b,f,t] = sum_c conj(w_c) * x_c(t), 256 threads ----
    float wr[8], wi[8];
    #pragma unroll
    for (int c = 0; c < 8; ++c) { wr[c] = wre[c]; wi[c] = wim[c]; }

    float2* outr = (float2*)out + (b*Ff + f)*P2;
    float2* outi = (float2*)out + (Bb*Ff)*P2 + (b*Ff + f)*P2;
    for (int pp = tid; pp < P2; pp += 256) {
        float rx = 0.f, ry = 0.f, ix = 0.f, iy = 0.f;
        #pragma unroll
        for (int c = 0; c < 8; ++c) {
            float2 a  = xr2[pp + c*cstride];
            float2 bb = xi2[pp + c*cstride];
            rx += wr[c]*a.x + wi[c]*bb.x;
            ry += wr[c]*a.y + wi[c]*bb.y;
            ix += wr[c]*bb.x - wi[c]*a.x;
            iy += wr[c]*bb.y - wi[c]*a.y;
        }
        outr[pp] = make_float2(rx, ry);
        outi[pp] = make_float2(ix, iy);
    }
}

extern "C" void kernel_launch(void* const* d_in, const int* in_sizes, int n_in,
                              void* d_out, int out_size, void* d_ws, size_t ws_size,
                              hipStream_t stream) {
    const float* smask = (const float*)d_in[0];
    const float* nmask = (const float*)d_in[1];
    const float* cmr   = (const float*)d_in[2];
    const float* cmi   = (const float*)d_in[3];
    float* ws = (float*)d_ws;
    float* pmax_s = ws;                 // 8*8*1500 = 96000 floats
    float* pmax_n = ws + 96000;         // 96000
    float* inv_s  = ws + 192000;        // 12000
    float* inv_n  = ws + 204000;        // 12000  (total 864 KB)

    mask_pmax<<<dim3(6, 8, 8), 256, 0, stream>>>(smask, nmask, pmax_s, pmax_n);
    mask_inv <<<dim3(6, 8),    256, 0, stream>>>(pmax_s, pmax_n, inv_s, inv_n);
    mvdr_main<<<BF, 256, 0, stream>>>(smask, nmask, cmr, cmi, inv_s, inv_n, (float*)d_out);
}